// Round 14
// baseline (251.819 us; speedup 1.0000x reference)
//
#include <hip/hip_runtime.h>

#define NB 16
#define NC 64
#define NN 4096
#define LOG2E 1.44269504088896f

typedef _Float16 half8 __attribute__((ext_vector_type(8)));
typedef float f32x16 __attribute__((ext_vector_type(16)));
typedef unsigned int uint4v __attribute__((ext_vector_type(4)));

#define MFMA(A, B, C) __builtin_amdgcn_mfma_f32_32x32x16_f16(A, B, C, 0, 0, 0)

// Workspace layout, in _Float16 units:
//   qT: [B][N][16]  (qhi[8], qlo[8])  -- pre-scaled by log2(e)
//   kT: [B][N][16]  (khi[8], klo[8])
//   vh: [B][C][N]
#define QT_OFF ((size_t)0)
#define KT_OFF ((size_t)NB * NN * 16)
#define VH_OFF ((size_t)2 * NB * NN * 16)

// ---------------- Kernel 1: fused QKV projection ----------------
// grid (256, 3) x 256. sel=0: q(log2e-scaled)+k hi/lo; sel=1: v[0:32); sel=2: v[32:64).
// 4-way partial sums keep dependent FMA chains 16 deep.
__global__ __launch_bounds__(256) void qkv_kernel(
    const float* __restrict__ x, const float* __restrict__ Wq,
    const float* __restrict__ Wk, const float* __restrict__ Wv,
    _Float16* __restrict__ qT, _Float16* __restrict__ kT, _Float16* __restrict__ vh)
{
    const int tid = threadIdx.x;
    const int blk = blockIdx.x;
    const int sel = blockIdx.y;
    const int b = blk >> 4;
    const int n = (blk & 15) * 256 + tid;

    const float* xb = x + (size_t)b * NC * NN + n;
    float xr[NC];
#pragma unroll
    for (int c = 0; c < NC; ++c) xr[c] = xb[(size_t)c * NN];

    if (sel == 0) {
        float qa[8], ka[8];
#pragma unroll
        for (int d = 0; d < 8; ++d) {
            float aq0 = 0.f, aq1 = 0.f, aq2 = 0.f, aq3 = 0.f;
            float ak0 = 0.f, ak1 = 0.f, ak2 = 0.f, ak3 = 0.f;
            const float* wq = Wq + d * NC;
            const float* wk = Wk + d * NC;
#pragma unroll
            for (int c = 0; c < NC; c += 4) {
                aq0 = fmaf(wq[c],     xr[c],     aq0);
                aq1 = fmaf(wq[c + 1], xr[c + 1], aq1);
                aq2 = fmaf(wq[c + 2], xr[c + 2], aq2);
                aq3 = fmaf(wq[c + 3], xr[c + 3], aq3);
                ak0 = fmaf(wk[c],     xr[c],     ak0);
                ak1 = fmaf(wk[c + 1], xr[c + 1], ak1);
                ak2 = fmaf(wk[c + 2], xr[c + 2], ak2);
                ak3 = fmaf(wk[c + 3], xr[c + 3], ak3);
            }
            qa[d] = ((aq0 + aq1) + (aq2 + aq3)) * LOG2E;   // exp2-domain scores
            ka[d] = (ak0 + ak1) + (ak2 + ak3);
        }
        half8 qhi, qlo, khi, klo;
#pragma unroll
        for (int d = 0; d < 8; ++d) {
            _Float16 hq = (_Float16)qa[d];
            qhi[d] = hq; qlo[d] = (_Float16)(qa[d] - (float)hq);
            _Float16 hk = (_Float16)ka[d];
            khi[d] = hk; klo[d] = (_Float16)(ka[d] - (float)hk);
        }
        _Float16* qr = qT + ((size_t)b * NN + n) * 16;
        *(half8*)qr = qhi; *(half8*)(qr + 8) = qlo;
        _Float16* kr = kT + ((size_t)b * NN + n) * 16;
        *(half8*)kr = khi; *(half8*)(kr + 8) = klo;
    } else {
        const int e0 = (sel - 1) * 32;
#pragma unroll 4
        for (int e = e0; e < e0 + 32; ++e) {
            float a0 = 0.f, a1 = 0.f, a2 = 0.f, a3 = 0.f;
            const float* wv = Wv + e * NC;
#pragma unroll
            for (int c = 0; c < NC; c += 4) {
                a0 = fmaf(wv[c],     xr[c],     a0);
                a1 = fmaf(wv[c + 1], xr[c + 1], a1);
                a2 = fmaf(wv[c + 2], xr[c + 2], a2);
                a3 = fmaf(wv[c + 3], xr[c + 3], a3);
            }
            vh[((size_t)b * NC + e) * NN + n] = (_Float16)((a0 + a1) + (a2 + a3));
        }
    }
}

// ---------------- Kernel 2: MFMA flash attention + residual ----------------
// grid 1024 x 256 (4 waves). Wave-pair p owns 32 queries; wave odd/even takes
// keys [odd*2048, odd*2048+2048). End merge of (m,l,acc) through LDS.
// Swapped score MFMA; PV B-frag via cvt_pkrtz + permlane32_swap; exp2 softmax.
__global__ __launch_bounds__(256) void attn_kernel(
    const float* __restrict__ x, const float* __restrict__ gamma,
    const _Float16* __restrict__ qT, const _Float16* __restrict__ kT,
    const _Float16* __restrict__ vh, float* __restrict__ out)
{
    __shared__ __attribute__((aligned(16))) float mrg[2][64][36];

    const int tid  = threadIdx.x;
    const int lane = tid & 63;
    const int wid  = tid >> 6;
    const int l31  = lane & 31;
    const int g    = lane >> 5;
    const int pair = wid >> 1;
    const int odd  = wid & 1;

    // bijective XCD swizzle (1024 % 8 == 0)
    const int blk  = blockIdx.x;
    const int virt = (blk & 7) * 128 + (blk >> 3);
    const int b    = virt >> 6;     // 64 blocks per batch (64 queries each)
    const int qt   = virt & 63;
    const int q    = qt * 64 + pair * 32 + l31;

    // Q B-frags (loop-invariant). B1 = [qhi;qhi], B2 = [qlo;0].
    const _Float16* qr = qT + ((size_t)b * NN + q) * 16;
    const half8 qb1 = *(const half8*)qr;
    const half8 qlo = *(const half8*)(qr + 8);
    half8 qb2;
#pragma unroll
    for (int i = 0; i < 8; ++i) qb2[i] = g ? (_Float16)0 : qlo[i];

    // K/V pointers, offset into this wave's key half
    const _Float16* kp  = kT + (size_t)b * NN * 16 + ((size_t)odd * 2048 + l31) * 16 + (size_t)g * 8;
    const _Float16* vp0 = vh + (size_t)b * NC * NN + (size_t)l31 * NN + odd * 2048 + (size_t)g * 8;
    const _Float16* vp1 = vp0 + (size_t)32 * NN;

    f32x16 acc0 = {}, acc1 = {};
    float mrun = -__builtin_inff();
    float lrun = 0.f;

    half8 ka = *(const half8*)kp;   // K frag, tile 0

#define NT (2048 / 32)
    for (int t = 0; t < NT; ++t) {
        const int off = t * 32;
        const half8 va00 = *(const half8*)(vp0 + off);
        const half8 va01 = *(const half8*)(vp0 + off + 16);
        const half8 va10 = *(const half8*)(vp1 + off);
        const half8 va11 = *(const half8*)(vp1 + off + 16);

        // scores (log2 domain): S = k . (q*log2e), hi/lo compensated
        f32x16 S = {};
        S = MFMA(ka, qb1, S);
        S = MFMA(ka, qb2, S);

        const int tn = (t + 1 < NT) ? (t + 1) : t;
        ka = *(const half8*)(kp + (size_t)tn * 512);

        const float s0 = S[0],  s1 = S[1],  s2 = S[2],  s3 = S[3];
        const float s4 = S[4],  s5 = S[5],  s6 = S[6],  s7 = S[7];
        const float s8 = S[8],  s9 = S[9],  s10 = S[10], s11 = S[11];
        const float s12 = S[12], s13 = S[13], s14 = S[14], s15 = S[15];

        float pmax = fmaxf(
            fmaxf(fmaxf(fmaxf(s0, s1), fmaxf(s2, s3)), fmaxf(fmaxf(s4, s5), fmaxf(s6, s7))),
            fmaxf(fmaxf(fmaxf(s8, s9), fmaxf(s10, s11)), fmaxf(fmaxf(s12, s13), fmaxf(s14, s15))));
        pmax = fmaxf(pmax, __shfl_xor(pmax, 32, 64));

        // defer-max (log2 units: 8 nats ~ 11.54)
        if (__any(pmax > mrun + 11.6f)) {
            const float mnew = fmaxf(mrun, pmax);
            const float rs = exp2f(mrun - mnew);   // first tile: 2^-inf = 0
            lrun *= rs;
#pragma unroll
            for (int r = 0; r < 16; ++r) { acc0[r] *= rs; acc1[r] *= rs; }
            mrun = mnew;
        }

        const float p0 = exp2f(s0 - mrun),  p1 = exp2f(s1 - mrun);
        const float p2 = exp2f(s2 - mrun),  p3 = exp2f(s3 - mrun);
        const float p4 = exp2f(s4 - mrun),  p5 = exp2f(s5 - mrun);
        const float p6 = exp2f(s6 - mrun),  p7 = exp2f(s7 - mrun);
        const float p8 = exp2f(s8 - mrun),  p9 = exp2f(s9 - mrun);
        const float p10 = exp2f(s10 - mrun), p11 = exp2f(s11 - mrun);
        const float p12 = exp2f(s12 - mrun), p13 = exp2f(s13 - mrun);
        const float p14 = exp2f(s14 - mrun), p15 = exp2f(s15 - mrun);

        float ls = (((p0 + p1) + (p2 + p3)) + ((p4 + p5) + (p6 + p7)))
                 + (((p8 + p9) + (p10 + p11)) + ((p12 + p13) + (p14 + p15)));
        ls += __shfl_xor(ls, 32, 64);
        lrun += ls;

        const unsigned int x0 = __builtin_bit_cast(unsigned int, __builtin_amdgcn_cvt_pkrtz(p0, p1));
        const unsigned int x1 = __builtin_bit_cast(unsigned int, __builtin_amdgcn_cvt_pkrtz(p2, p3));
        const unsigned int x2 = __builtin_bit_cast(unsigned int, __builtin_amdgcn_cvt_pkrtz(p4, p5));
        const unsigned int x3 = __builtin_bit_cast(unsigned int, __builtin_amdgcn_cvt_pkrtz(p6, p7));
        const unsigned int x4 = __builtin_bit_cast(unsigned int, __builtin_amdgcn_cvt_pkrtz(p8, p9));
        const unsigned int x5 = __builtin_bit_cast(unsigned int, __builtin_amdgcn_cvt_pkrtz(p10, p11));
        const unsigned int x6 = __builtin_bit_cast(unsigned int, __builtin_amdgcn_cvt_pkrtz(p12, p13));
        const unsigned int x7 = __builtin_bit_cast(unsigned int, __builtin_amdgcn_cvt_pkrtz(p14, p15));

        // swap(A,B): out0 = {A@g0 | B_g0@g1}, out1 = {A_g1@g0 | B@g1}
        auto r0 = __builtin_amdgcn_permlane32_swap(x0, x2, false, false);
        auto r1 = __builtin_amdgcn_permlane32_swap(x1, x3, false, false);
        auto r2 = __builtin_amdgcn_permlane32_swap(x4, x6, false, false);
        auto r3 = __builtin_amdgcn_permlane32_swap(x5, x7, false, false);
        const uint4v w0 = {(unsigned int)r0[0], (unsigned int)r1[0],
                           (unsigned int)r0[1], (unsigned int)r1[1]};   // keys 0..15
        const uint4v w1 = {(unsigned int)r2[0], (unsigned int)r3[0],
                           (unsigned int)r2[1], (unsigned int)r3[1]};   // keys 16..31
        const half8 pv0 = __builtin_bit_cast(half8, w0);
        const half8 pv1 = __builtin_bit_cast(half8, w1);

        acc0 = MFMA(va00, pv0, acc0);
        acc0 = MFMA(va01, pv1, acc0);
        acc1 = MFMA(va10, pv0, acc1);
        acc1 = MFMA(va11, pv1, acc1);
    }

    // ---- merge key-halves: odd waves publish, even waves combine + write ----
    if (odd) {
        float* r = &mrg[pair][lane][0];
#pragma unroll
        for (int i = 0; i < 16; ++i) r[i] = acc0[i];
#pragma unroll
        for (int i = 0; i < 16; ++i) r[16 + i] = acc1[i];
        r[32] = mrun; r[33] = lrun;
    }
    __syncthreads();
    if (!odd) {
        const float* r = &mrg[pair][lane][0];
        const float mB = r[32], lB = r[33];
        const float mN = fmaxf(mrun, mB);
        const float eA = exp2f(mrun - mN);
        const float eB = exp2f(mB - mN);
        const float l  = lrun * eA + lB * eB;
        const float linv = 1.0f / l;
        const float gm = gamma[0];
#pragma unroll
        for (int rr = 0; rr < 16; ++rr) {
            const int crow = (rr & 3) + 8 * (rr >> 2) + 4 * g;
            const float a0 = acc0[rr] * eA + r[rr] * eB;
            const float a1 = acc1[rr] * eA + r[16 + rr] * eB;
            const size_t i0 = ((size_t)b * NC + crow) * NN + q;
            out[i0] = fmaf(gm, a0 * linv, x[i0]);
            const size_t i1 = ((size_t)b * NC + crow + 32) * NN + q;
            out[i1] = fmaf(gm, a1 * linv, x[i1]);
        }
    }
}

extern "C" void kernel_launch(void* const* d_in, const int* in_sizes, int n_in,
                              void* d_out, int out_size, void* d_ws, size_t ws_size,
                              hipStream_t stream) {
    const float* x     = (const float*)d_in[0];
    const float* Wq    = (const float*)d_in[1];
    const float* Wk    = (const float*)d_in[2];
    const float* Wv    = (const float*)d_in[3];
    const float* gamma = (const float*)d_in[4];
    float* out = (float*)d_out;
    _Float16* ws = (_Float16*)d_ws;

    _Float16* qT = ws + QT_OFF;
    _Float16* kT = ws + KT_OFF;
    _Float16* vh = ws + VH_OFF;

    qkv_kernel<<<dim3(NB * (NN / 256), 3), dim3(256), 0, stream>>>(x, Wq, Wk, Wv, qT, kT, vh);
    attn_kernel<<<dim3(NB * (NN / 64)), dim3(256), 0, stream>>>(x, gamma, qT, kT, vh, out);
}